// Round 14
// baseline (127.338 us; speedup 1.0000x reference)
//
#include <hip/hip_runtime.h>
#include <hip/hip_bf16.h>
#include <math.h>

#define B_ 8192
#define L_ 512
#define BL_ (B_ * L_)
#define KT_ 1536

using bf16x8 = __attribute__((ext_vector_type(8))) short;
using f32x4  = __attribute__((ext_vector_type(4))) float;

__device__ __forceinline__ float gelu_f(float v) {
    return 0.5f * v * (1.0f + erff(v * 0.70710678118654752f));
}
__device__ __forceinline__ float bf2f(unsigned short u) {
    return __uint_as_float(((unsigned int)u) << 16);
}
__device__ __forceinline__ unsigned short f2bf(float f) {
    unsigned int x = __float_as_uint(f);
    x += 0x7fffu + ((x >> 16) & 1u);   // RNE
    return (unsigned short)(x >> 16);
}
__device__ __forceinline__ void gload16(const void* g, void* l) {
    __builtin_amdgcn_global_load_lds(
        (const __attribute__((address_space(1))) unsigned int*)g,
        (__attribute__((address_space(3))) unsigned int*)l, 16, 0, 0);
}

// fused conv1(1->3ch,k=3,pad1)+GELU -> h1 bf16 [b][c][i]  AND  LayerNorm -> lnx bf16
__global__ __launch_bounds__(256) void k_pre(const float* __restrict__ x,
        const float* __restrict__ c1w, const float* __restrict__ c1b,
        const float* __restrict__ lg, const float* __restrict__ lbias,
        unsigned short* __restrict__ h1, unsigned short* __restrict__ lnx) {
    __shared__ float xs[512];
    __shared__ float red[8];
    const int tid = threadIdx.x;
    const long b = blockIdx.x;
    const float* xr = x + (b << 9);
    float x0 = xr[tid], x1 = xr[tid + 256];
    xs[tid] = x0; xs[tid + 256] = x1;
    float s = x0 + x1, ss = x0 * x0 + x1 * x1;
#pragma unroll
    for (int off = 32; off > 0; off >>= 1) {
        s += __shfl_xor(s, off);
        ss += __shfl_xor(ss, off);
    }
    if ((tid & 63) == 0) { red[tid >> 6] = s; red[4 + (tid >> 6)] = ss; }
    __syncthreads();
    s  = red[0] + red[1] + red[2] + red[3];
    ss = red[4] + red[5] + red[6] + red[7];
    const float mu = s * (1.f / 512.f);
    const float rs = rsqrtf(ss * (1.f / 512.f) - mu * mu + 1e-5f);
    float w[9], cb[3];
#pragma unroll
    for (int j = 0; j < 9; ++j) w[j] = c1w[j];
#pragma unroll
    for (int j = 0; j < 3; ++j) cb[j] = c1b[j];
#pragma unroll
    for (int half = 0; half < 2; ++half) {
        const int i = tid + (half << 8);
        const float xm = i ? xs[i - 1] : 0.f;
        const float xc = xs[i];
        const float xp = (i != 511) ? xs[i + 1] : 0.f;
        unsigned short* hb = h1 + b * KT_ + i;
#pragma unroll
        for (int c = 0; c < 3; ++c) {
            float v = w[c * 3] * xm + w[c * 3 + 1] * xc + w[c * 3 + 2] * xp + cb[c];
            hb[(long)c << 9] = f2bf(gelu_f(v));
        }
        lnx[(b << 9) + i] = f2bf(fmaf((xc - mu) * rs, lg[i], lbias[i]));
    }
}

// weight prep: Weff bf16 [512][1536] (collapsed conv3+poly), w1/w2 -> bf16 [N][K]
// + twiddle tables (blocks 0-1): tabd(512 double2), tab(512 float2), tab32(32 float2)
__global__ __launch_bounds__(256) void k_prep(const float* __restrict__ c3w,
        const float* __restrict__ w1, const float* __restrict__ w2,
        unsigned short* __restrict__ weff, unsigned short* __restrict__ w1b,
        unsigned short* __restrict__ w2b,
        double2* __restrict__ tabd, float2* __restrict__ tab,
        float2* __restrict__ tab32) {
    int idx = blockIdx.x * 256 + threadIdx.x;      // 512*512
    if (idx < 512) {
        double sv, cv;
        sincos((double)idx * (3.14159265358979323846 / 256.0), &sv, &cv);
        tabd[idx] = make_double2(cv, sv);
        tab[idx] = make_float2((float)cv, (float)sv);
        if ((idx & 15) == 0) tab32[idx >> 4] = make_float2((float)cv, (float)sv);
    }
    int o = idx >> 9, i = idx & 511;
    const float* t = c3w + (size_t)idx * 3;
    float t0 = t[0], t1 = t[1], t2 = t[2];
    size_t base = (size_t)o * KT_ + i;
    weff[base]        = f2bf(0.25f * t0 + 0.5f * t1);
    weff[base + 512]  = f2bf(0.125f * t0 + 0.25f * t1 + 0.5f * t2);
    weff[base + 1024] = f2bf(0.125f * t1 + 0.25f * t2);
    w1b[idx] = f2bf(w1[idx]);
    w2b[idx] = f2bf(w2[idx]);
}

// MFMA GEMM, 2-phase double-buffered (T3 minimum recipe): issue next-tile
// global_load_lds BEFORE computing current tile; one barrier per K-step.
// BM=128 BN=64 BK=64, 4 waves, wave tile 64x32 (4x2 frags 16x16x32).
// LDS [2][*][64]: slot-XOR swizzle slot^=(row&7); source pre-swizzled,
// dest linear (= base + lane*16), read swizzled (rule #21).
template<int EMODE, int KD>
__global__ __launch_bounds__(256) void k_mgemm(
        const unsigned short* __restrict__ A, const unsigned short* __restrict__ W,
        const float* __restrict__ bias, float sbias,
        const float* __restrict__ xres, void* __restrict__ Cp) {
    __shared__ short As[2][128][64];
    __shared__ short Bs[2][64][64];
    const int tid = threadIdx.x;
    const int lane = tid & 63;
    const int wid = tid >> 6;
    const int m0 = blockIdx.x << 7;
    const int n0 = blockIdx.y << 6;
    const int wm = (wid & 1) << 6;
    const int wn = (wid >> 1) << 5;
    f32x4 acc[4][2] = {};

    const int srow = tid >> 3;          // 0..31 per segment
    const int schunk = tid & 7;         // 16B chunk within 64-col row
    const unsigned short* Ab = A + (size_t)m0 * KD;
    const unsigned short* Wb = W + (size_t)n0 * KD;
    const int frow = lane & 15;
    const int fsw = frow & 7;
    const int s0 = lane >> 4;           // k-subslot 0..3
    const int nt = KD / 64;

#define STAGE_TILE(buf, k0)                                                   \
    {                                                                         \
        _Pragma("unroll")                                                     \
        for (int seg = 0; seg < 4; ++seg) {                                   \
            const int r = (seg << 5) + srow;                                  \
            const int c = (schunk ^ (r & 7)) << 3;                            \
            gload16(Ab + (size_t)r * KD + (k0) + c, &As[buf][r][schunk << 3]);\
        }                                                                     \
        _Pragma("unroll")                                                     \
        for (int seg = 0; seg < 2; ++seg) {                                   \
            const int r = (seg << 5) + srow;                                  \
            const int c = (schunk ^ (r & 7)) << 3;                            \
            gload16(Wb + (size_t)r * KD + (k0) + c, &Bs[buf][r][schunk << 3]);\
        }                                                                     \
    }

    STAGE_TILE(0, 0);
    __syncthreads();                    // buf0 ready (vmcnt drain at barrier)
    for (int t = 0; t < nt; ++t) {
        const int cur = t & 1;
        if (t + 1 < nt) STAGE_TILE(cur ^ 1, (t + 1) * 64);   // overlap w/ MFMA
#pragma unroll
        for (int kk = 0; kk < 2; ++kk) {
            bf16x8 af[4], bfr[2];
            const int sl = (kk << 2) + s0;
#pragma unroll
            for (int m = 0; m < 4; ++m)
                af[m] = *(const bf16x8*)&As[cur][wm + (m << 4) + frow][(sl ^ fsw) << 3];
#pragma unroll
            for (int n = 0; n < 2; ++n)
                bfr[n] = *(const bf16x8*)&Bs[cur][wn + (n << 4) + frow][(sl ^ fsw) << 3];
#pragma unroll
            for (int m = 0; m < 4; ++m)
#pragma unroll
                for (int n = 0; n < 2; ++n)
                    acc[m][n] = __builtin_amdgcn_mfma_f32_16x16x32_bf16(af[m], bfr[n], acc[m][n], 0, 0, 0);
        }
        __syncthreads();                // next buf ready + cur reads done
    }
#undef STAGE_TILE

    const int col0 = n0 + wn + (lane & 15);
    const int rbase = m0 + wm + ((lane >> 4) << 2);
#pragma unroll
    for (int n = 0; n < 2; ++n) {
        const int col = col0 + (n << 4);
        const float bz = sbias * bias[col];
#pragma unroll
        for (int m = 0; m < 4; ++m) {
#pragma unroll
            for (int r = 0; r < 4; ++r) {
                const size_t row = rbase + (m << 4) + r;
                float v = acc[m][n][r] + bz;
                if (EMODE == 0) {
                    ((float*)Cp)[row * 512 + col] = v;
                } else if (EMODE == 1) {
                    ((unsigned short*)Cp)[row * 512 + col] = f2bf(gelu_f(v));
                } else {
                    ((float*)Cp)[row * 512 + col] = v + xres[row * 512 + col];
                }
            }
        }
    }
}

// season v5: 2 rows per block, strength-reduced twiddle indices.
// Per-bin arithmetic order identical to v1-v4 -> bit-identical output.
__global__ __launch_bounds__(256) void k_season(const float* __restrict__ x,
        const double2* __restrict__ gtabd, const float2* __restrict__ gtab,
        const float2* __restrict__ gtab32,
        float* __restrict__ out1, float* __restrict__ out0) {
    __shared__ float2 xp[2][256];   // p = 8*t1 + t0 -> (x[16t1+t0], x[16t1+t0+8])
    __shared__ float2 tab[512];     // synthesis twiddles (linear)
    __shared__ float2 Ys[2][512];   // [row][t0*32+rr]
    __shared__ unsigned long long wkey[2][4][5];
    __shared__ float2 wval[2][4][5];

    const int tid = threadIdx.x;
    const int w = tid >> 6, l = tid & 63;
    const long b = (long)blockIdx.x << 1;              // rows b, b+1
    const float* xr0 = x + (b << 9);
    const float* xr1 = xr0 + 512;

    // staging (one barrier)
    {
        const int t1s = tid >> 3, t0s = tid & 7;
        const int g = (t1s << 4) + t0s;
        xp[0][tid] = make_float2(xr0[g], xr0[g + 8]);
        xp[1][tid] = make_float2(xr1[g], xr1[g + 8]);
        tab[tid] = gtab[tid];
        tab[tid + 256] = gtab[tid + 256];
    }
    __syncthreads();                                   // barrier 1

    // stage 1: lane computes Y[t0][rr], Y[t0+8][rr] for both rows
    const int rr = (w << 3) + (l & 7);
    const int t0 = l >> 3;                             // 0..7
    float ra0 = 0.f, ia0 = 0.f, rb0 = 0.f, ib0 = 0.f;  // row0
    float ra1 = 0.f, ia1 = 0.f, rb1 = 0.f, ib1 = 0.f;  // row1
    int e32 = 0;
#pragma unroll
    for (int t1 = 0; t1 < 32; ++t1) {
        float2 wt = gtab32[e32];                       // (rr*t1)&31, L1-resident
        e32 = (e32 + rr) & 31;
        float2 v0 = xp[0][(t1 << 3) + t0];
        float2 v1 = xp[1][(t1 << 3) + t0];
        ra0 = fmaf(v0.x, wt.x, ra0); ia0 = fmaf(v0.x, wt.y, ia0);
        rb0 = fmaf(v0.y, wt.x, rb0); ib0 = fmaf(v0.y, wt.y, ib0);
        ra1 = fmaf(v1.x, wt.x, ra1); ia1 = fmaf(v1.x, wt.y, ia1);
        rb1 = fmaf(v1.y, wt.x, rb1); ib1 = fmaf(v1.y, wt.y, ib1);
    }
    // same-wave write->read (no barrier needed)
    Ys[0][(t0 << 5) + rr] = make_float2(ra0, -ia0);
    Ys[0][((t0 + 8) << 5) + rr] = make_float2(rb0, -ib0);
    Ys[1][(t0 << 5) + rr] = make_float2(ra1, -ia1);
    Ys[1][((t0 + 8) << 5) + rr] = make_float2(rb1, -ib1);

    // stage 2 (double): lane handles bin k for both rows
    const int k = ((l >> 3) << 5) + rr;                // 0..255, k=0 invalid
    double xre0 = 0.0, xim0 = 0.0, xre1 = 0.0, xim1 = 0.0;
    int e = 0;
#pragma unroll
    for (int t0i = 0; t0i < 16; ++t0i) {
        float2 y0 = Ys[0][(t0i << 5) + rr];
        float2 y1 = Ys[1][(t0i << 5) + rr];
        double2 wt = gtabd[e];                         // (k*t0i)&511
        e = (e + k) & 511;
        xre0 += (double)y0.x * wt.x + (double)y0.y * wt.y;
        xim0 += (double)y0.y * wt.x - (double)y0.x * wt.y;
        xre1 += (double)y1.x * wt.x + (double)y1.y * wt.y;
        xim1 += (double)y1.y * wt.x - (double)y1.x * wt.y;
    }

    // packed keys: mag top-52 bits | (4095-k) -> tie breaks to lower k
    unsigned long long key0 = 0, key1 = 0;
    if (k != 0) {
        double m0 = xre0 * xre0 + xim0 * xim0;
        double m1 = xre1 * xre1 + xim1 * xim1;
        key0 = (__double_as_longlong(m0) & ~0xFFFull) | (unsigned long long)(4095 - k);
        key1 = (__double_as_longlong(m1) & ~0xFFFull) | (unsigned long long)(4095 - k);
    }
    const float fre0 = (float)xre0, fim0 = (float)xim0;
    const float fre1 = (float)xre1, fim1 = (float)xim1;

    // wave-local top-5, both rows interleaved (no barriers)
    for (int rnd = 0; rnd < 5; ++rnd) {
        unsigned long long rk0 = key0, rk1 = key1;
#pragma unroll
        for (int off = 32; off > 0; off >>= 1) {
            unsigned long long o0 = __shfl_xor(rk0, off);
            unsigned long long o1 = __shfl_xor(rk1, off);
            rk0 = (o0 > rk0) ? o0 : rk0;
            rk1 = (o1 > rk1) ? o1 : rk1;
        }
        if (key0 == rk0 && rk0 != 0ull) {
            wkey[0][w][rnd] = rk0; wval[0][w][rnd] = make_float2(fre0, fim0); key0 = 0;
        }
        if (key1 == rk1 && rk1 != 0ull) {
            wkey[1][w][rnd] = rk1; wval[1][w][rnd] = make_float2(fre1, fim1); key1 = 0;
        }
    }
    __syncthreads();                                   // barrier 2

    // per row: merge 4 sorted lists of 5, then synthesis (+ zero out0)
#pragma unroll
    for (int row = 0; row < 2; ++row) {
        float4 sel[5];
        int h0 = 0, h1 = 0, h2 = 0, h3 = 0;
#pragma unroll
        for (int rnd = 0; rnd < 5; ++rnd) {
            unsigned long long c0 = wkey[row][0][h0], c1 = wkey[row][1][h1];
            unsigned long long c2 = wkey[row][2][h2], c3 = wkey[row][3][h3];
            unsigned long long bk = c0; int bw = 0;
            if (c1 > bk) { bk = c1; bw = 1; }
            if (c2 > bk) { bk = c2; bw = 2; }
            if (c3 > bk) { bk = c3; bw = 3; }
            const int hs = (bw == 0) ? h0 : (bw == 1) ? h1 : (bw == 2) ? h2 : h3;
            float2 v = wval[row][bw][hs];
            h0 += (bw == 0); h1 += (bw == 1); h2 += (bw == 2); h3 += (bw == 3);
            const int kk = 4095 - (int)(bk & 0xFFFull);
            sel[rnd] = make_float4((float)kk, v.x, v.y, 0.f);
        }
        const long ro = ((b + row) << 9);
#pragma unroll
        for (int half = 0; half < 2; ++half) {
            int t = tid + (half << 8);
            float acc = 0.f;
#pragma unroll
            for (int j = 0; j < 5; ++j) {
                float4 sj = sel[j];
                int kj = (int)sj.x;
                float2 wt = tab[(kj * t) & 511];
                acc += sj.y * wt.x - sj.z * wt.y;
            }
            out1[ro + t] = 2.f * acc;
            out0[ro + t] = 0.f;
        }
    }
}

extern "C" void kernel_launch(void* const* d_in, const int* in_sizes, int n_in,
                              void* d_out, int out_size, void* d_ws, size_t ws_size,
                              hipStream_t stream) {
    const float* x   = (const float*)d_in[0];
    const float* c1w = (const float*)d_in[1];
    const float* c1b = (const float*)d_in[2];
    const float* c3w = (const float*)d_in[3];
    const float* c3b = (const float*)d_in[4];
    const float* w1  = (const float*)d_in[5];
    const float* b1  = (const float*)d_in[6];
    const float* w2  = (const float*)d_in[7];
    const float* b2  = (const float*)d_in[8];
    const float* lg  = (const float*)d_in[9];
    const float* lb  = (const float*)d_in[10];

    float* out  = (float*)d_out;
    float* out1 = out + (long)BL_;          // season
    float* out2 = out + 2L * BL_;           // trend
    float* out3 = out + 3L * BL_;           // e

    // d_ws: twiddle tables (12.5 KB)
    double2* tabd = (double2*)d_ws;
    float2* tab   = (float2*)((char*)d_ws + 8192);
    float2* tab32 = (float2*)((char*)d_ws + 12288);

    // scratch in d_out (lifetimes ordered by the stream):
    unsigned short* h1   = (unsigned short*)d_out;          // 24 MB [0,24M): till trend GEMM
    unsigned short* weff = h1 + (size_t)B_ * KT_;           // [24,25.5M)
    unsigned short* w1b  = weff + (size_t)L_ * KT_;         // [25.5,26M)
    unsigned short* w2b  = w1b + (size_t)L_ * L_;           // [26,26.5M): till mgemm2
    unsigned short* lnx  = (unsigned short*)(out3);         // 8 MB in out3: till mgemm1
    unsigned short* m1   = (unsigned short*)d_out;          // 8 MB [0,8M): after h1 dead

    // 1) fused conv1+GELU -> h1 and LayerNorm -> lnx
    k_pre<<<B_, 256, 0, stream>>>(x, c1w, c1b, lg, lb, h1, lnx);
    // 2) weights -> bf16 + twiddle tables
    k_prep<<<L_ * L_ / 256, 256, 0, stream>>>(c3w, w1, w2, weff, w1b, w2b,
                                              tabd, tab, tab32);
    // 3) trend GEMM -> out2
    k_mgemm<0, KT_><<<dim3(64, 8), 256, 0, stream>>>(h1, weff, c3b, 0.875f, nullptr, out2);
    // 4) MLP1: GELU(lnx @ w1^T + b1) -> m1 (bf16; h1 now dead)
    k_mgemm<1, 512><<<dim3(64, 8), 256, 0, stream>>>(lnx, w1b, b1, 1.0f, nullptr, m1);
    // 5) MLP2: m1 @ w2^T + b2 + x -> out3 (lnx dead)
    k_mgemm<2, 512><<<dim3(64, 8), 256, 0, stream>>>(m1, w2b, b2, 1.0f, x, out3);
    // 6) season (2 rows/block) -> out1, zero -> out0 (all scratch dead)
    k_season<<<B_ / 2, 256, 0, stream>>>(x, tabd, tab, tab32, out1, out);
}

// Round 15
// 115.528 us; speedup vs baseline: 1.1022x; 1.1022x over previous
//
#include <hip/hip_runtime.h>
#include <hip/hip_bf16.h>
#include <math.h>

#define B_ 8192
#define L_ 512
#define BL_ (B_ * L_)
#define KT_ 1536

using bf16x8 = __attribute__((ext_vector_type(8))) short;
using f32x4  = __attribute__((ext_vector_type(4))) float;

__device__ __forceinline__ float gelu_f(float v) {
    return 0.5f * v * (1.0f + erff(v * 0.70710678118654752f));
}
__device__ __forceinline__ float bf2f(unsigned short u) {
    return __uint_as_float(((unsigned int)u) << 16);
}
__device__ __forceinline__ unsigned short f2bf(float f) {
    unsigned int x = __float_as_uint(f);
    x += 0x7fffu + ((x >> 16) & 1u);   // RNE
    return (unsigned short)(x >> 16);
}
__device__ __forceinline__ void gload16(const void* g, void* l) {
    __builtin_amdgcn_global_load_lds(
        (const __attribute__((address_space(1))) unsigned int*)g,
        (__attribute__((address_space(3))) unsigned int*)l, 16, 0, 0);
}

// fused: blocks [0,B_) = conv1+GELU -> h1 AND LayerNorm -> lnx (one row each);
// blocks [B_, B_+1024) = weight prep (Weff/w1b/w2b) + twiddle tables.
__global__ __launch_bounds__(256) void k_fused_pre(const float* __restrict__ x,
        const float* __restrict__ c1w, const float* __restrict__ c1b,
        const float* __restrict__ lg, const float* __restrict__ lbias,
        unsigned short* __restrict__ h1, unsigned short* __restrict__ lnx,
        const float* __restrict__ c3w, const float* __restrict__ w1,
        const float* __restrict__ w2, unsigned short* __restrict__ weff,
        unsigned short* __restrict__ w1b, unsigned short* __restrict__ w2b,
        double2* __restrict__ tabd, float2* __restrict__ tab,
        float2* __restrict__ tab32) {
    const int tid = threadIdx.x;
    if (blockIdx.x >= B_) {
        // ---- prep path ----
        int idx = (blockIdx.x - B_) * 256 + tid;       // 512*512
        if (idx < 512) {
            double sv, cv;
            sincos((double)idx * (3.14159265358979323846 / 256.0), &sv, &cv);
            tabd[idx] = make_double2(cv, sv);
            tab[idx] = make_float2((float)cv, (float)sv);
            if ((idx & 15) == 0) tab32[idx >> 4] = make_float2((float)cv, (float)sv);
        }
        int o = idx >> 9, i = idx & 511;
        const float* t = c3w + (size_t)idx * 3;
        float t0 = t[0], t1 = t[1], t2 = t[2];
        size_t base = (size_t)o * KT_ + i;
        weff[base]        = f2bf(0.25f * t0 + 0.5f * t1);
        weff[base + 512]  = f2bf(0.125f * t0 + 0.25f * t1 + 0.5f * t2);
        weff[base + 1024] = f2bf(0.125f * t1 + 0.25f * t2);
        w1b[idx] = f2bf(w1[idx]);
        w2b[idx] = f2bf(w2[idx]);
        return;
    }
    // ---- pre path ----
    __shared__ float xs[512];
    __shared__ float red[8];
    const long b = blockIdx.x;
    const float* xr = x + (b << 9);
    float x0 = xr[tid], x1 = xr[tid + 256];
    xs[tid] = x0; xs[tid + 256] = x1;
    float s = x0 + x1, ss = x0 * x0 + x1 * x1;
#pragma unroll
    for (int off = 32; off > 0; off >>= 1) {
        s += __shfl_xor(s, off);
        ss += __shfl_xor(ss, off);
    }
    if ((tid & 63) == 0) { red[tid >> 6] = s; red[4 + (tid >> 6)] = ss; }
    __syncthreads();
    s  = red[0] + red[1] + red[2] + red[3];
    ss = red[4] + red[5] + red[6] + red[7];
    const float mu = s * (1.f / 512.f);
    const float rs = rsqrtf(ss * (1.f / 512.f) - mu * mu + 1e-5f);
    float w[9], cb[3];
#pragma unroll
    for (int j = 0; j < 9; ++j) w[j] = c1w[j];
#pragma unroll
    for (int j = 0; j < 3; ++j) cb[j] = c1b[j];
#pragma unroll
    for (int half = 0; half < 2; ++half) {
        const int i = tid + (half << 8);
        const float xm = i ? xs[i - 1] : 0.f;
        const float xc = xs[i];
        const float xp = (i != 511) ? xs[i + 1] : 0.f;
        unsigned short* hb = h1 + b * KT_ + i;
#pragma unroll
        for (int c = 0; c < 3; ++c) {
            float v = w[c * 3] * xm + w[c * 3 + 1] * xc + w[c * 3 + 2] * xp + cb[c];
            hb[(long)c << 9] = f2bf(gelu_f(v));
        }
        lnx[(b << 9) + i] = f2bf(fmaf((xc - mu) * rs, lg[i], lbias[i]));
    }
}

// MFMA GEMM (R13 single-buffer version): C = A * W^T + sbias*bias
// BM=128 BN=64 BK=64, 4 waves, wave tile 64x32 (4x2 frags 16x16x32, 2 k-substeps)
// LDS [*][64]: slot-XOR swizzle slot^=(row&7); source pre-swizzled, dest
// linear, read swizzled (rule #21).
template<int EMODE, int KD>
__global__ __launch_bounds__(256) void k_mgemm(
        const unsigned short* __restrict__ A, const unsigned short* __restrict__ W,
        const float* __restrict__ bias, float sbias,
        const float* __restrict__ xres, void* __restrict__ Cp) {
    __shared__ short As[128][64];
    __shared__ short Bs[64][64];
    const int tid = threadIdx.x;
    const int lane = tid & 63;
    const int wid = tid >> 6;
    const int m0 = blockIdx.x << 7;
    const int n0 = blockIdx.y << 6;
    const int wm = (wid & 1) << 6;
    const int wn = (wid >> 1) << 5;
    f32x4 acc[4][2] = {};

    const int srow = tid >> 3;          // 0..31 per segment
    const int schunk = tid & 7;         // 16B chunk within 64-col row
    const unsigned short* Ab = A + (size_t)m0 * KD;
    const unsigned short* Wb = W + (size_t)n0 * KD;
    const int frow = lane & 15;
    const int fsw = frow & 7;
    const int s0 = lane >> 4;           // k-subslot 0..3

    for (int k0 = 0; k0 < KD; k0 += 64) {
        __syncthreads();
#pragma unroll
        for (int seg = 0; seg < 4; ++seg) {
            const int r = (seg << 5) + srow;
            const int c = (schunk ^ (r & 7)) << 3;
            gload16(Ab + (size_t)r * KD + k0 + c, &As[r][schunk << 3]);
        }
#pragma unroll
        for (int seg = 0; seg < 2; ++seg) {
            const int r = (seg << 5) + srow;
            const int c = (schunk ^ (r & 7)) << 3;
            gload16(Wb + (size_t)r * KD + k0 + c, &Bs[r][schunk << 3]);
        }
        __syncthreads();
#pragma unroll
        for (int kk = 0; kk < 2; ++kk) {
            bf16x8 af[4], bfr[2];
            const int sl = (kk << 2) + s0;
#pragma unroll
            for (int m = 0; m < 4; ++m)
                af[m] = *(const bf16x8*)&As[wm + (m << 4) + frow][(sl ^ fsw) << 3];
#pragma unroll
            for (int n = 0; n < 2; ++n)
                bfr[n] = *(const bf16x8*)&Bs[wn + (n << 4) + frow][(sl ^ fsw) << 3];
#pragma unroll
            for (int m = 0; m < 4; ++m)
#pragma unroll
                for (int n = 0; n < 2; ++n)
                    acc[m][n] = __builtin_amdgcn_mfma_f32_16x16x32_bf16(af[m], bfr[n], acc[m][n], 0, 0, 0);
        }
    }

    const int col0 = n0 + wn + (lane & 15);
    const int rbase = m0 + wm + ((lane >> 4) << 2);
#pragma unroll
    for (int n = 0; n < 2; ++n) {
        const int col = col0 + (n << 4);
        const float bz = sbias * bias[col];
#pragma unroll
        for (int m = 0; m < 4; ++m) {
#pragma unroll
            for (int r = 0; r < 4; ++r) {
                const size_t row = rbase + (m << 4) + r;
                float v = acc[m][n][r] + bz;
                if (EMODE == 0) {
                    ((float*)Cp)[row * 512 + col] = v;
                } else if (EMODE == 1) {
                    ((unsigned short*)Cp)[row * 512 + col] = f2bf(gelu_f(v));
                } else {
                    ((float*)Cp)[row * 512 + col] = v + xres[row * 512 + col];
                }
            }
        }
    }
}

// season v5: 2 rows per block, strength-reduced twiddle indices.
// Per-bin arithmetic order identical to v1-v4 -> bit-identical output.
__global__ __launch_bounds__(256) void k_season(const float* __restrict__ x,
        const double2* __restrict__ gtabd, const float2* __restrict__ gtab,
        const float2* __restrict__ gtab32,
        float* __restrict__ out1, float* __restrict__ out0) {
    __shared__ float2 xp[2][256];   // p = 8*t1 + t0 -> (x[16t1+t0], x[16t1+t0+8])
    __shared__ float2 tab[512];     // synthesis twiddles (linear)
    __shared__ float2 Ys[2][512];   // [row][t0*32+rr]
    __shared__ unsigned long long wkey[2][4][5];
    __shared__ float2 wval[2][4][5];

    const int tid = threadIdx.x;
    const int w = tid >> 6, l = tid & 63;
    const long b = (long)blockIdx.x << 1;              // rows b, b+1
    const float* xr0 = x + (b << 9);
    const float* xr1 = xr0 + 512;

    // staging (one barrier)
    {
        const int t1s = tid >> 3, t0s = tid & 7;
        const int g = (t1s << 4) + t0s;
        xp[0][tid] = make_float2(xr0[g], xr0[g + 8]);
        xp[1][tid] = make_float2(xr1[g], xr1[g + 8]);
        tab[tid] = gtab[tid];
        tab[tid + 256] = gtab[tid + 256];
    }
    __syncthreads();                                   // barrier 1

    // stage 1: lane computes Y[t0][rr], Y[t0+8][rr] for both rows
    const int rr = (w << 3) + (l & 7);
    const int t0 = l >> 3;                             // 0..7
    float ra0 = 0.f, ia0 = 0.f, rb0 = 0.f, ib0 = 0.f;  // row0
    float ra1 = 0.f, ia1 = 0.f, rb1 = 0.f, ib1 = 0.f;  // row1
    int e32 = 0;
#pragma unroll
    for (int t1 = 0; t1 < 32; ++t1) {
        float2 wt = gtab32[e32];                       // (rr*t1)&31, L1-resident
        e32 = (e32 + rr) & 31;
        float2 v0 = xp[0][(t1 << 3) + t0];
        float2 v1 = xp[1][(t1 << 3) + t0];
        ra0 = fmaf(v0.x, wt.x, ra0); ia0 = fmaf(v0.x, wt.y, ia0);
        rb0 = fmaf(v0.y, wt.x, rb0); ib0 = fmaf(v0.y, wt.y, ib0);
        ra1 = fmaf(v1.x, wt.x, ra1); ia1 = fmaf(v1.x, wt.y, ia1);
        rb1 = fmaf(v1.y, wt.x, rb1); ib1 = fmaf(v1.y, wt.y, ib1);
    }
    // same-wave write->read (no barrier needed)
    Ys[0][(t0 << 5) + rr] = make_float2(ra0, -ia0);
    Ys[0][((t0 + 8) << 5) + rr] = make_float2(rb0, -ib0);
    Ys[1][(t0 << 5) + rr] = make_float2(ra1, -ia1);
    Ys[1][((t0 + 8) << 5) + rr] = make_float2(rb1, -ib1);

    // stage 2 (double): lane handles bin k for both rows
    const int k = ((l >> 3) << 5) + rr;                // 0..255, k=0 invalid
    double xre0 = 0.0, xim0 = 0.0, xre1 = 0.0, xim1 = 0.0;
    int e = 0;
#pragma unroll
    for (int t0i = 0; t0i < 16; ++t0i) {
        float2 y0 = Ys[0][(t0i << 5) + rr];
        float2 y1 = Ys[1][(t0i << 5) + rr];
        double2 wt = gtabd[e];                         // (k*t0i)&511
        e = (e + k) & 511;
        xre0 += (double)y0.x * wt.x + (double)y0.y * wt.y;
        xim0 += (double)y0.y * wt.x - (double)y0.x * wt.y;
        xre1 += (double)y1.x * wt.x + (double)y1.y * wt.y;
        xim1 += (double)y1.y * wt.x - (double)y1.x * wt.y;
    }

    // packed keys: mag top-52 bits | (4095-k) -> tie breaks to lower k
    unsigned long long key0 = 0, key1 = 0;
    if (k != 0) {
        double m0 = xre0 * xre0 + xim0 * xim0;
        double m1 = xre1 * xre1 + xim1 * xim1;
        key0 = (__double_as_longlong(m0) & ~0xFFFull) | (unsigned long long)(4095 - k);
        key1 = (__double_as_longlong(m1) & ~0xFFFull) | (unsigned long long)(4095 - k);
    }
    const float fre0 = (float)xre0, fim0 = (float)xim0;
    const float fre1 = (float)xre1, fim1 = (float)xim1;

    // wave-local top-5, both rows interleaved (no barriers)
    for (int rnd = 0; rnd < 5; ++rnd) {
        unsigned long long rk0 = key0, rk1 = key1;
#pragma unroll
        for (int off = 32; off > 0; off >>= 1) {
            unsigned long long o0 = __shfl_xor(rk0, off);
            unsigned long long o1 = __shfl_xor(rk1, off);
            rk0 = (o0 > rk0) ? o0 : rk0;
            rk1 = (o1 > rk1) ? o1 : rk1;
        }
        if (key0 == rk0 && rk0 != 0ull) {
            wkey[0][w][rnd] = rk0; wval[0][w][rnd] = make_float2(fre0, fim0); key0 = 0;
        }
        if (key1 == rk1 && rk1 != 0ull) {
            wkey[1][w][rnd] = rk1; wval[1][w][rnd] = make_float2(fre1, fim1); key1 = 0;
        }
    }
    __syncthreads();                                   // barrier 2

    // per row: merge 4 sorted lists of 5, then synthesis (+ zero out0)
#pragma unroll
    for (int row = 0; row < 2; ++row) {
        float4 sel[5];
        int h0 = 0, h1 = 0, h2 = 0, h3 = 0;
#pragma unroll
        for (int rnd = 0; rnd < 5; ++rnd) {
            unsigned long long c0 = wkey[row][0][h0], c1 = wkey[row][1][h1];
            unsigned long long c2 = wkey[row][2][h2], c3 = wkey[row][3][h3];
            unsigned long long bk = c0; int bw = 0;
            if (c1 > bk) { bk = c1; bw = 1; }
            if (c2 > bk) { bk = c2; bw = 2; }
            if (c3 > bk) { bk = c3; bw = 3; }
            const int hs = (bw == 0) ? h0 : (bw == 1) ? h1 : (bw == 2) ? h2 : h3;
            float2 v = wval[row][bw][hs];
            h0 += (bw == 0); h1 += (bw == 1); h2 += (bw == 2); h3 += (bw == 3);
            const int kk = 4095 - (int)(bk & 0xFFFull);
            sel[rnd] = make_float4((float)kk, v.x, v.y, 0.f);
        }
        const long ro = ((b + row) << 9);
#pragma unroll
        for (int half = 0; half < 2; ++half) {
            int t = tid + (half << 8);
            float acc = 0.f;
#pragma unroll
            for (int j = 0; j < 5; ++j) {
                float4 sj = sel[j];
                int kj = (int)sj.x;
                float2 wt = tab[(kj * t) & 511];
                acc += sj.y * wt.x - sj.z * wt.y;
            }
            out1[ro + t] = 2.f * acc;
            out0[ro + t] = 0.f;
        }
    }
}

extern "C" void kernel_launch(void* const* d_in, const int* in_sizes, int n_in,
                              void* d_out, int out_size, void* d_ws, size_t ws_size,
                              hipStream_t stream) {
    const float* x   = (const float*)d_in[0];
    const float* c1w = (const float*)d_in[1];
    const float* c1b = (const float*)d_in[2];
    const float* c3w = (const float*)d_in[3];
    const float* c3b = (const float*)d_in[4];
    const float* w1  = (const float*)d_in[5];
    const float* b1  = (const float*)d_in[6];
    const float* w2  = (const float*)d_in[7];
    const float* b2  = (const float*)d_in[8];
    const float* lg  = (const float*)d_in[9];
    const float* lb  = (const float*)d_in[10];

    float* out  = (float*)d_out;
    float* out1 = out + (long)BL_;          // season
    float* out2 = out + 2L * BL_;           // trend
    float* out3 = out + 3L * BL_;           // e

    // d_ws: twiddle tables (12.5 KB)
    double2* tabd = (double2*)d_ws;
    float2* tab   = (float2*)((char*)d_ws + 8192);
    float2* tab32 = (float2*)((char*)d_ws + 12288);

    // scratch in d_out (lifetimes ordered by the stream):
    unsigned short* h1   = (unsigned short*)d_out;          // 24 MB [0,24M): till trend GEMM
    unsigned short* weff = h1 + (size_t)B_ * KT_;           // [24,25.5M)
    unsigned short* w1b  = weff + (size_t)L_ * KT_;         // [25.5,26M)
    unsigned short* w2b  = w1b + (size_t)L_ * L_;           // [26,26.5M): till mgemm2
    unsigned short* lnx  = (unsigned short*)(out3);         // 8 MB in out3: till mgemm1
    unsigned short* m1   = (unsigned short*)d_out;          // 8 MB [0,8M): after h1 dead

    // 1) fused: conv1+GELU -> h1, LayerNorm -> lnx, weights -> bf16, tables
    k_fused_pre<<<B_ + 1024, 256, 0, stream>>>(x, c1w, c1b, lg, lb, h1, lnx,
                                               c3w, w1, w2, weff, w1b, w2b,
                                               tabd, tab, tab32);
    // 2) trend GEMM -> out2
    k_mgemm<0, KT_><<<dim3(64, 8), 256, 0, stream>>>(h1, weff, c3b, 0.875f, nullptr, out2);
    // 3) MLP1: GELU(lnx @ w1^T + b1) -> m1 (bf16; h1 now dead)
    k_mgemm<1, 512><<<dim3(64, 8), 256, 0, stream>>>(lnx, w1b, b1, 1.0f, nullptr, m1);
    // 4) MLP2: m1 @ w2^T + b2 + x -> out3 (lnx dead)
    k_mgemm<2, 512><<<dim3(64, 8), 256, 0, stream>>>(m1, w2b, b2, 1.0f, x, out3);
    // 5) season (2 rows/block) -> out1, zero -> out0 (all scratch dead)
    k_season<<<B_ / 2, 256, 0, stream>>>(x, tabd, tab, tab32, out1, out);
}